// Round 9
// baseline (1754.428 us; speedup 1.0000x reference)
//
#include <hip/hip_runtime.h>
#include <math.h>

// Problem constants
#define ST 64      // sequence length T
#define NBAT 64    // batch B
#define ED 256     // embedding dim E
#define HD 512     // hidden dim H
#define G4 2048    // 4*H
#define VO 32000   // vocab
#define NBLK 16                  // recurrent blocks (sync domain)
#define UPB 32                   // hidden units per block
#define CPB 128                  // gate cols per block (4*UPB), interleaved n=4u+g
#define SLOTU32 (NBAT * HD / 2)  // u32s per h slot (64 KB)

typedef unsigned int u32;
typedef __bf16 bf16;
typedef bf16 bf16x8 __attribute__((ext_vector_type(8)));
typedef float f32x4 __attribute__((ext_vector_type(4)));

__device__ __forceinline__ float fsigm(float x) { return 1.f / (1.f + __expf(-x)); }
__device__ __forceinline__ float ftanh(float x) { return 2.f / (1.f + __expf(-2.f * x)) - 1.f; }

// ---------------- prep kernels ----------------

__global__ void k_lengths(const int* __restrict__ toks, int* __restrict__ len) {
  int b = threadIdx.x;
  if (b < NBAT) {
    int n = 0;
    for (int t = 0; t < ST; ++t) n += (toks[b * ST + t] != 0) ? 1 : 0;
    len[b] = n;
  }
}

__global__ void k_cast(const float* __restrict__ src, bf16* __restrict__ dst, int n) {
  int i = blockIdx.x * blockDim.x + threadIdx.x;
  if (i < n) dst[i] = (bf16)src[i];
}

__global__ void k_bias(const float* __restrict__ a, const float* __restrict__ b,
                       float* __restrict__ o) {
  int i = blockIdx.x * blockDim.x + threadIdx.x;
  if (i < G4) o[i] = a[i] + b[i];
}

// encX[t][b][e] = emb[toks[b][t]][e]; decX[t][b][e] = emb[t==0 ? 1 : toks[b][t-1]][e]
__global__ void k_gather(const int* __restrict__ toks, const float* __restrict__ emb,
                         bf16* __restrict__ encX, bf16* __restrict__ decX) {
  int i = blockIdx.x * blockDim.x + threadIdx.x;
  if (i >= ST * NBAT * ED) return;
  int e = i % ED;
  int tb = i / ED;
  int b = tb % NBAT;
  int t = tb / NBAT;
  int te = toks[b * ST + t];
  encX[i] = (bf16)emb[te * ED + e];
  int td = (t == 0) ? 1 : toks[b * ST + t - 1];
  decX[i] = (bf16)emb[td * ED + e];
}

// ---------------- bulk x-projection GEMM ----------------
// xg[step][slab][b][nl] = X[step][b] @ Wih(phase)^T + bsum(phase), bf16.
// Col layout inside a 128-col slab is gate-INTERLEAVED: nl = 4*u + g, i.e.
// Wih row = g*HD + 32*slab + u. M = 128 steps * 64 b = 8192 (steps 0..63
// encoder with enc weights, 64..127 decoder with dec weights; 128-row tiles
// never straddle the phase boundary). K = 256, fully staged in LDS.
__global__ __launch_bounds__(256, 1) void k_xg(
    const bf16* __restrict__ encX, const bf16* __restrict__ decX,
    const bf16* __restrict__ WihE, const bf16* __restrict__ WihD,
    const float* __restrict__ bsumE, const float* __restrict__ bsumD,
    bf16* __restrict__ xg)
{
  __shared__ __align__(16) bf16 As[128][ED + 8];
  __shared__ __align__(16) bf16 Bs[128][ED + 8];
  const int tid  = threadIdx.x;
  const int lane = tid & 63;
  const int wid  = tid >> 6;
  const int wm   = wid >> 1, wn = wid & 1;
  const int bx   = blockIdx.x;         // slab 0..15
  const int bm   = blockIdx.y * 128;   // row tile
  const int r16  = lane & 15, kh = lane >> 4, kc = kh * 8;
  const bool dec = (bm >= ST * NBAT);
  const bf16* Asrc  = dec ? decX + (size_t)(bm - ST * NBAT) * ED
                          : encX + (size_t)bm * ED;
  const bf16* Wih   = dec ? WihD : WihE;
  const float* bsum = dec ? bsumD : bsumE;

  for (int idx = tid; idx < 128 * (ED / 8); idx += 256) {
    int rrow = idx >> 5;
    int k8   = (idx & 31) * 8;
    *(bf16x8*)&As[rrow][k8] = *(const bf16x8*)(Asrc + (size_t)rrow * ED + k8);
    int wrow = (rrow & 3) * HD + UPB * bx + (rrow >> 2);  // interleaved
    *(bf16x8*)&Bs[rrow][k8] = *(const bf16x8*)(Wih + (size_t)wrow * ED + k8);
  }

  f32x4 acc[4][4];
  #pragma unroll
  for (int j = 0; j < 4; ++j) {
    int nl = 64 * wn + 16 * j + r16;
    float bias = bsum[(nl & 3) * HD + UPB * bx + (nl >> 2)];
    #pragma unroll
    for (int i = 0; i < 4; ++i) acc[i][j] = (f32x4){bias, bias, bias, bias};
  }
  __syncthreads();

  #pragma unroll
  for (int kk = 0; kk < ED / 32; ++kk) {
    bf16x8 af[4], bfv[4];
    #pragma unroll
    for (int i = 0; i < 4; ++i)
      af[i] = *(const bf16x8*)(&As[64 * wm + 16 * i + r16][kk * 32 + kc]);
    #pragma unroll
    for (int j = 0; j < 4; ++j)
      bfv[j] = *(const bf16x8*)(&Bs[64 * wn + 16 * j + r16][kk * 32 + kc]);
    #pragma unroll
    for (int i = 0; i < 4; ++i)
      #pragma unroll
      for (int j = 0; j < 4; ++j)
        acc[i][j] = __builtin_amdgcn_mfma_f32_16x16x32_bf16(af[i], bfv[j], acc[i][j], 0, 0, 0);
  }

  #pragma unroll
  for (int j = 0; j < 4; ++j) {
    int nl = 64 * wn + 16 * j + r16;
    #pragma unroll
    for (int i = 0; i < 4; ++i) {
      #pragma unroll
      for (int r = 0; r < 4; ++r) {
        int m = bm + 64 * wm + 16 * i + kh * 4 + r;
        int step = m >> 6, b = m & 63;
        xg[(((size_t)step * NBLK + bx) * NBAT + b) * CPB + nl] = (bf16)acc[i][j][r];
      }
    }
  }
}

// ---------------- persistent LSTM kernel: 16 blocks ----------------
//
// Block bk owns 32 hidden units (gate-interleaved cols n = 4u+g) -> only
// Whh slice (131 KB) lives in LDS; x-part+bias precomputed by k_xg.
// 8 waves: wm = w&3 (batch m-frag), wn = w>>2; wave covers cols
// [64*wn, 64*wn+64) via 4 jj n-frags. Per step, per wave: 16 xg loads
// (acc-init), 16 A-frag cold loads from h slot, 64 MFMAs, in-register cell
// (3 shfl_xor per gate-quad; all 4 lanes of a quad compute redundantly),
// packed bypass stores.
//
// Sync (16-block domain): flags = 16 u32 = ONE cache line.
//   fire: __syncthreads (drains every wave's bypass-store acks at the
//         coherence point), tid0 relaxed-stores flags[blk]=step+1.
//   wait: wave 0 polls the single flag line (16 pollers chip-wide --
//         rounds 7/8 showed poller count is the congestion lever), then
//         LDS-broadcasts `go`; other waves spin on LDS (no fabric traffic).
//   h slots are per-step (never reused) -> consumer loads are plain cached
//   cold-miss loads, fresh by construction; dispatch-boundary invalidate
//   covers graph replays. No WAR hazard, no fences in the loop.
__global__ __launch_bounds__(512, 1) void k_lstm16(
    const bf16* __restrict__ WhhE, const bf16* __restrict__ WhhD,
    const bf16* __restrict__ xg,   // [128][16 slab][64 b][128] bf16
    const int* __restrict__ len,
    u32* __restrict__ hx,          // [129][16 prod][64 b][16] u32 h slots
    u32* flags)                    // [16] per-block progress
{
  __shared__ __align__(16) bf16 Wr[CPB][HD + 8];  // 133 KB
  __shared__ u32 go_lds;

  const int tid  = threadIdx.x;
  const int lane = tid & 63;
  const int wid  = tid >> 6;
  const int wm   = wid & 3;
  const int wn   = wid >> 2;
  const int blk  = blockIdx.x;
  const int r16  = lane & 15;
  const int kh   = lane >> 4;
  const int kc   = kh * 8;
  const bool gb0 = lane & 1;   // gate-index bit 0 (g = lane&3)
  const bool gb1 = lane & 2;   // gate-index bit 1

  if (tid == 0) go_lds = 0;

  int lenr[4];
  #pragma unroll
  for (int r = 0; r < 4; ++r) lenr[r] = len[16 * wm + kh * 4 + r];

  float c[4][4], hprev[4][4];
  #pragma unroll
  for (int jj = 0; jj < 4; ++jj)
    #pragma unroll
    for (int r = 0; r < 4; ++r) hprev[jj][r] = 0.f;

  for (int phase = 0; phase < 2; ++phase) {
    const bf16* Whh = phase ? WhhD : WhhE;
    for (int idx = tid; idx < CPB * (HD / 8); idx += 512) {
      int n  = idx >> 6;
      int k8 = (idx & 63) * 8;
      int row = (n & 3) * HD + UPB * blk + (n >> 2);  // interleaved cols
      *(bf16x8*)&Wr[n][k8] = *(const bf16x8*)(Whh + (size_t)row * HD + k8);
    }
    #pragma unroll
    for (int jj = 0; jj < 4; ++jj)
      #pragma unroll
      for (int r = 0; r < 4; ++r) c[jj][r] = 0.f;  // dec carries z via slot 64, c=0
    __syncthreads();  // Wr + go_lds published

    for (int t = 0; t < ST; ++t) {
      const int step = phase * ST + t;

      // ---- xg acc-init: issued before the wait, overlaps detection ----
      f32x4 acc[4];
      const bf16* xgs = xg + ((size_t)step * NBLK + blk) * (NBAT * CPB);
      #pragma unroll
      for (int jj = 0; jj < 4; ++jj) {
        #pragma unroll
        for (int r = 0; r < 4; ++r) {
          int b = 16 * wm + kh * 4 + r;
          acc[jj][r] = (float)xgs[b * CPB + 64 * wn + 16 * jj + r16];
        }
      }

      // ---- wait for h(step): 1-line fabric poll by wave0, LDS bounce ----
      if (step > 0) {
        if (wid == 0) {
          u32 f = __hip_atomic_load(&flags[lane & 15], __ATOMIC_RELAXED,
                                    __HIP_MEMORY_SCOPE_AGENT);
          while (!__all((int)(f >= (u32)step))) {
            __builtin_amdgcn_s_sleep(1);
            f = __hip_atomic_load(&flags[lane & 15], __ATOMIC_RELAXED,
                                  __HIP_MEMORY_SCOPE_AGENT);
          }
          if (lane == 0)
            __hip_atomic_store(&go_lds, (u32)step, __ATOMIC_RELAXED,
                               __HIP_MEMORY_SCOPE_WORKGROUP);
        } else {
          u32 g = __hip_atomic_load(&go_lds, __ATOMIC_RELAXED,
                                    __HIP_MEMORY_SCOPE_WORKGROUP);
          while (g < (u32)step) {
            __builtin_amdgcn_s_sleep(1);
            g = __hip_atomic_load(&go_lds, __ATOMIC_RELAXED,
                                  __HIP_MEMORY_SCOPE_WORKGROUP);
          }
        }
        __builtin_amdgcn_fence(__ATOMIC_ACQUIRE, "wavefront");
        __builtin_amdgcn_sched_barrier(0);
      }

      // ---- h-part: K=512 = 16 chunks, chunk kk = producer kk's 32 units ----
      const bf16* hsl = (const bf16*)(hx + (size_t)step * SLOTU32);
      #pragma unroll
      for (int kk = 0; kk < 16; ++kk) {
        bf16x8 av = *(const bf16x8*)(hsl + kk * 2048 + (16 * wm + r16) * 32 + kc);
        #pragma unroll
        for (int jj = 0; jj < 4; ++jj) {
          bf16x8 bv = *(const bf16x8*)(&Wr[64 * wn + 16 * jj + r16][kk * 32 + kc]);
          acc[jj] = __builtin_amdgcn_mfma_f32_16x16x32_bf16(av, bv, acc[jj], 0, 0, 0);
        }
      }

      // ---- in-register cell (gate quad = 4 adjacent lanes) ----
      u32* hxout = hx + (size_t)(step + 1) * SLOTU32;
      #pragma unroll
      for (int jj = 0; jj < 4; ++jj) {
        #pragma unroll
        for (int r = 0; r < 4; ++r) {
          float v  = acc[jj][r];          // own gate g0 = lane&3
          float v1 = __shfl_xor(v, 1);    // gate g0^1
          float v2 = __shfl_xor(v, 2);    // gate g0^2
          float v3 = __shfl_xor(v1, 2);   // gate g0^3
          float I = gb1 ? (gb0 ? v3 : v2) : (gb0 ? v1 : v);
          float F = gb1 ? (gb0 ? v2 : v3) : (gb0 ? v  : v1);
          float G = gb1 ? (gb0 ? v1 : v ) : (gb0 ? v3 : v2);
          float O = gb1 ? (gb0 ? v  : v1) : (gb0 ? v2 : v3);
          float cn = fsigm(F) * c[jj][r] + fsigm(I) * ftanh(G);
          float hn = fsigm(O) * ftanh(cn);
          bool upd = (phase == 1) || (t < lenr[r]);
          c[jj][r] = upd ? cn : c[jj][r];
          float hv = upd ? hn : hprev[jj][r];
          bf16 hb = (bf16)hv;
          float hvr = (float)hb;          // keep bf16-rounded for mask replay
          hprev[jj][r] = hvr;
          float hot = __shfl_xor(hvr, 4); // partner unit u^1 (same gate slot)
          if ((lane & 7) == 0) {          // g==0 and u even: owns the u32 pair
            union { u32 u; bf16 h[2]; } pk;
            pk.h[0] = hb; pk.h[1] = (bf16)hot;
            int b = 16 * wm + kh * 4 + r;
            int i32 = blk * (NBAT * 16) + b * 16 + 8 * wn + 2 * jj + (r16 >> 3);
            __hip_atomic_store(&hxout[i32], pk.u, __ATOMIC_RELAXED,
                               __HIP_MEMORY_SCOPE_AGENT);
          }
        }
      }

      // drain all waves' bypass stores (vmcnt(0) per wave), then fire
      __syncthreads();
      if (step < 2 * ST - 1 && tid == 0)
        __hip_atomic_store(&flags[blk], (u32)(step + 1), __ATOMIC_RELAXED,
                           __HIP_MEMORY_SCOPE_AGENT);
    }
    __syncthreads();  // all waves done with this phase's Wr before restage
  }
}

// ---------------- output projection GEMM ----------------
// logits[b][t][v] = sum_h hs[t][b][h] * lin_W[v][h] + lin_b[v]
// A read DIRECTLY from h slots 65..128: h(t)[b][k] at slot(65+t), offset
// (k>>5)*2048 + b*32 + (k&31) (bf16). B staged from f32 linW with inline
// bf16 cvt (saves the 33 MB WbL ws buffer). XCD-aware bijective swizzle.
__global__ __launch_bounds__(256, 2) void k_logits(
    const u32* __restrict__ hx, const float* __restrict__ linW,
    const float* __restrict__ linb, float* __restrict__ out)
{
  __shared__ __align__(16) bf16 As[128][72];
  __shared__ __align__(16) bf16 Bs[128][72];
  const int tid  = threadIdx.x;
  const int lane = tid & 63;
  const int wid  = tid >> 6;
  const int wm   = wid >> 1, wn = wid & 1;

  const int flat = blockIdx.y * gridDim.x + blockIdx.x;   // 0..7999
  const int swz  = (flat & 7) * 1000 + (flat >> 3);       // bijective (8000%8==0)
  const int bn   = (swz % (VO / 128)) * 128;
  const int bm   = (swz / (VO / 128)) * 128;

  const int r16  = lane & 15, kh = lane >> 4;
  const bf16* hxb = (const bf16*)hx;

  f32x4 acc[4][4];
  #pragma unroll
  for (int i = 0; i < 4; ++i)
    #pragma unroll
    for (int j = 0; j < 4; ++j) acc[i][j] = (f32x4){0.f, 0.f, 0.f, 0.f};

  const int srow = tid >> 3;        // 0..31
  const int scol = (tid & 7) * 8;   // 0..56

  for (int kt = 0; kt < HD / 64; ++kt) {
    __syncthreads();
    #pragma unroll
    for (int p = 0; p < 4; ++p) {
      int row = p * 32 + srow;
      int m = bm + row, tt = m >> 6, b = m & 63;
      int k = kt * 64 + scol;
      *(bf16x8*)(&As[row][scol]) = *(const bf16x8*)(
          hxb + (size_t)(ST + 1 + tt) * (2 * SLOTU32) + (k >> 5) * 2048 + b * 32 + (k & 31));
      const float* bsrc = linW + (size_t)(bn + row) * HD + k;
      f32x4 x0 = *(const f32x4*)bsrc;
      f32x4 x1 = *(const f32x4*)(bsrc + 4);
      bf16x8 bv;
      #pragma unroll
      for (int e = 0; e < 4; ++e) { bv[e] = (bf16)x0[e]; bv[4 + e] = (bf16)x1[e]; }
      *(bf16x8*)(&Bs[row][scol]) = bv;
    }
    __syncthreads();
    #pragma unroll
    for (int kk = 0; kk < 2; ++kk) {
      bf16x8 af[4], bfv[4];
      #pragma unroll
      for (int i = 0; i < 4; ++i)
        af[i] = *(const bf16x8*)(&As[64 * wm + 16 * i + r16][kk * 32 + kh * 8]);
      #pragma unroll
      for (int j = 0; j < 4; ++j)
        bfv[j] = *(const bf16x8*)(&Bs[64 * wn + 16 * j + r16][kk * 32 + kh * 8]);
      #pragma unroll
      for (int i = 0; i < 4; ++i)
        #pragma unroll
        for (int j = 0; j < 4; ++j)
          acc[i][j] = __builtin_amdgcn_mfma_f32_16x16x32_bf16(af[i], bfv[j], acc[i][j], 0, 0, 0);
    }
  }

  #pragma unroll
  for (int j = 0; j < 4; ++j) {
    int ncol = bn + 64 * wn + 16 * j + r16;
    float bias = linb[ncol];
    #pragma unroll
    for (int i = 0; i < 4; ++i) {
      int mbase = bm + 64 * wm + 16 * i + kh * 4;
      #pragma unroll
      for (int r = 0; r < 4; ++r) {
        int m = mbase + r;
        int b = m & 63, t = m >> 6;
        out[(size_t)(b * ST + t) * VO + ncol] = acc[i][j][r] + bias;
      }
    }
  }
}

// ---------------- host ----------------

extern "C" void kernel_launch(void* const* d_in, const int* in_sizes, int n_in,
                              void* d_out, int out_size, void* d_ws, size_t ws_size,
                              hipStream_t stream) {
  const int*   toks = (const int*)d_in[0];
  const float* emb  = (const float*)d_in[1];
  const float* eWih = (const float*)d_in[2];
  const float* eWhh = (const float*)d_in[3];
  const float* ebih = (const float*)d_in[4];
  const float* ebhh = (const float*)d_in[5];
  const float* dWih = (const float*)d_in[6];
  const float* dWhh = (const float*)d_in[7];
  const float* dbih = (const float*)d_in[8];
  const float* dbhh = (const float*)d_in[9];
  const float* linW = (const float*)d_in[10];
  const float* linb = (const float*)d_in[11];
  float* out = (float*)d_out;

  char* ws = (char*)d_ws;
  size_t off = 0;
  auto alloc = [&](size_t bytes) {
    void* p = ws + off;
    off = (off + bytes + 255) & ~(size_t)255;
    return p;
  };
  bf16* encX  = (bf16*)alloc((size_t)ST * NBAT * ED * 2);
  bf16* decX  = (bf16*)alloc((size_t)ST * NBAT * ED * 2);
  bf16* WihEb = (bf16*)alloc((size_t)G4 * ED * 2);
  bf16* WhhEb = (bf16*)alloc((size_t)G4 * HD * 2);
  bf16* WihDb = (bf16*)alloc((size_t)G4 * ED * 2);
  bf16* WhhDb = (bf16*)alloc((size_t)G4 * HD * 2);
  float* bsumE = (float*)alloc(G4 * 4);
  float* bsumD = (float*)alloc(G4 * 4);
  bf16* xg    = (bf16*)alloc((size_t)2 * ST * NBAT * G4 * 2);    // 33.5 MB
  u32*  hx    = (u32*)alloc((size_t)(2 * ST + 1) * SLOTU32 * 4); // 129 x 64 KB
  int*  len   = (int*)alloc(NBAT * 4);
  u32*  flags = (u32*)alloc(256);

  // slot 0 (h(0)=0) + flags must be clean every launch
  hipMemsetAsync(hx, 0, (size_t)SLOTU32 * 4, stream);
  hipMemsetAsync(flags, 0, 256, stream);

  k_lengths<<<1, 64, 0, stream>>>(toks, len);
  k_bias<<<(G4 + 255) / 256, 256, 0, stream>>>(ebih, ebhh, bsumE);
  k_bias<<<(G4 + 255) / 256, 256, 0, stream>>>(dbih, dbhh, bsumD);
  k_cast<<<(G4 * ED + 255) / 256, 256, 0, stream>>>(eWih, WihEb, G4 * ED);
  k_cast<<<(G4 * HD + 255) / 256, 256, 0, stream>>>(eWhh, WhhEb, G4 * HD);
  k_cast<<<(G4 * ED + 255) / 256, 256, 0, stream>>>(dWih, WihDb, G4 * ED);
  k_cast<<<(G4 * HD + 255) / 256, 256, 0, stream>>>(dWhh, WhhDb, G4 * HD);
  k_gather<<<(ST * NBAT * ED + 255) / 256, 256, 0, stream>>>(toks, emb, encX, decX);

  k_xg<<<dim3(NBLK, 2 * ST * NBAT / 128), 256, 0, stream>>>(
      encX, decX, WihEb, WihDb, bsumE, bsumD, xg);

  k_lstm16<<<NBLK, 512, 0, stream>>>(WhhEb, WhhDb, xg, len, hx, flags);

  k_logits<<<dim3(VO / 128, (ST * NBAT) / 128), 256, 0, stream>>>(
      hx, linW, linb, out);
}

// Round 10
// 998.736 us; speedup vs baseline: 1.7566x; 1.7566x over previous
//
#include <hip/hip_runtime.h>
#include <math.h>

// Problem constants
#define ST 64      // sequence length T
#define NBAT 64    // batch B
#define ED 256     // embedding dim E
#define HD 512     // hidden dim H
#define G4 2048    // 4*H
#define VO 32000   // vocab
#define NWORK 64               // worker blocks
#define SLOT32 (NBAT * HD / 2) // u32s per h slot (64 KB)

typedef unsigned int u32;
typedef __bf16 bf16;
typedef bf16 bf16x8 __attribute__((ext_vector_type(8)));
typedef float f32x4 __attribute__((ext_vector_type(4)));

__device__ __forceinline__ float sigm(float x) { return 1.f / (1.f + expf(-x)); }

// ---------------- prep kernels ----------------

__global__ void k_lengths(const int* __restrict__ toks, int* __restrict__ len) {
  int b = threadIdx.x;
  if (b < NBAT) {
    int n = 0;
    for (int t = 0; t < ST; ++t) n += (toks[b * ST + t] != 0) ? 1 : 0;
    len[b] = n;
  }
}

__global__ void k_cast(const float* __restrict__ src, bf16* __restrict__ dst, int n) {
  int i = blockIdx.x * blockDim.x + threadIdx.x;
  if (i < n) dst[i] = (bf16)src[i];
}

__global__ void k_bias(const float* __restrict__ a, const float* __restrict__ b,
                       float* __restrict__ o) {
  int i = blockIdx.x * blockDim.x + threadIdx.x;
  if (i < G4) o[i] = a[i] + b[i];
}

// encX[t][b][e] = emb[toks[b][t]][e]; decX[t][b][e] = emb[t==0 ? 1 : toks[b][t-1]][e]
__global__ void k_gather(const int* __restrict__ toks, const float* __restrict__ emb,
                         bf16* __restrict__ encX, bf16* __restrict__ decX) {
  int i = blockIdx.x * blockDim.x + threadIdx.x;
  if (i >= ST * NBAT * ED) return;
  int e = i % ED;
  int tb = i / ED;
  int b = tb % NBAT;
  int t = tb / NBAT;
  int te = toks[b * ST + t];
  encX[i] = (bf16)emb[te * ED + e];
  int td = (t == 0) ? 1 : toks[b * ST + t - 1];
  decX[i] = (bf16)emb[td * ED + e];
}

// ---------------- persistent LSTM kernel ----------------
//
// Sync: direct dense-flag poll by wave 0 only + LDS broadcast.
//   fire(v):  __syncthreads (each wave s_waitcnt vmcnt(0) -> bypass h-stores
//             acked at the coherence point), tid0 relaxed-stores flags[blk]=v.
//             flags = 64 contiguous u32 -> 4 cache lines.
//   wait(v):  wave 0: lane l polls flags[l] (one load across 4 lines) until
//             __all(>= v), then lane0 stores go_lds = v. Waves 1-7 spin on
//             go_lds (LDS only -- zero fabric traffic). 64 pollers chip-wide
//             (round-7 class; round 8's 512 pollers on these lines was the
//             regression). No aggregator middle hop, no post-wait barrier:
//             each wave self-synchronizes.
//   fence(acquire,wavefront)+sched_barrier(0) after the wait so the h-loads
//   cannot be speculated above it.
//
// h exchange: per-step slots hx[step][prod][b][8] (block-major).
//   Producer block writes ONE contiguous 1 KB run of relaxed agent-scope
//   bypass stores (full-line writes, no partial-line RMW). Consumer
//   A-fragment = one 16 B chunk at (4kk+hi)*1024 + arow*16, plain cached
//   load: slot is touched exactly once per launch -> cold in L1/L2 by
//   construction -> demand-fill from the coherence point cannot be stale.
//   First-toucher fills L2, the duplicate wn-wave hits it. No inv/wbl2.
//   Decoder h additionally plain-stored to hs[t][b][h] for k_logits
//   (dispatch boundary publishes it).
//
// Grid: 64 blocks x 512 threads. Block bk owns hidden units u0..u0+7
// (u0=8*bk) for all 4 gates -> 32 gate columns. Gates tile per step:
// [64 batch x 32 cols], K = 512 (h) + 256 (x). 8 waves: wave w -> m-frag
// (w&3), n-frag (w>>2). Gate col order: [i*8 | f*8 | g*8 | o*8].
__global__ __launch_bounds__(512, 2) void k_lstm(
    const bf16* __restrict__ encX, const bf16* __restrict__ decX,
    const bf16* __restrict__ WihE, const bf16* __restrict__ WhhE,
    const bf16* __restrict__ WihD, const bf16* __restrict__ WhhD,
    const float* __restrict__ bsumE, const float* __restrict__ bsumD,
    const int* __restrict__ len,
    u32* __restrict__ hx32,    // [2*ST+1][NWORK][NBAT][8/2] per-step h slots
    u32* __restrict__ hs32,    // [ST][NBAT][HD/2] decoder h (plain stores)
    u32* flags)                // [64] dense worker progress
{
  // +8 pad per row keeps b128 fragment reads spread over banks
  __shared__ __align__(16) bf16 Wr[32][HD + 8];
  __shared__ __align__(16) bf16 Wx[32][ED + 8];
  __shared__ float gl[64][33];
  __shared__ u32 go_lds;

  const int tid  = threadIdx.x;
  const int lane = tid & 63;
  const int wid  = tid >> 6;
  const int blk  = blockIdx.x;
  const int wm   = wid & 3;        // m-fragment (batch rows 16*wm..)
  const int wn   = wid >> 2;       // n-fragment (cols 16*wn..), 0..1
  const int u0   = blk * 8;
  const int r16  = lane & 15;
  const int kc   = (lane >> 4) * 8;
  const int hi   = lane >> 4;      // which 8-chunk of the 32-K slice
  const int arow = 16 * wm + r16;  // batch row for A-frags
  const int brow = 16 * wn + r16;  // LDS row for B-frags

  // epilogue mapping: 256 threads, one (batch, unit-pair) per thread
  const int eb   = (tid & 255) >> 2;   // 0..63
  const int j2   = (tid & 3) * 2;      // unit pair base within 8 owned units
  const int elen = len[eb];

  if (tid == 0) go_lds = 0;
  u32 hp = 0;  // packed h pair; carries z across the phase switch

  for (int phase = 0; phase < 2; ++phase) {
    const bf16* Wih  = phase ? WihD : WihE;
    const bf16* Whh  = phase ? WhhD : WhhE;
    const float* bsum = phase ? bsumD : bsumE;
    const bf16* Xall = phase ? decX : encX;

    // weight slices -> LDS (rows: gate q = n>>3, unit u0+(n&7))
    for (int idx = tid; idx < 32 * HD; idx += 512) {
      int n = idx >> 9, k = idx & (HD - 1);
      Wr[n][k] = Whh[((n >> 3) * HD + u0 + (n & 7)) * HD + k];
    }
    for (int idx = tid; idx < 32 * ED; idx += 512) {
      int n = idx >> 8, k = idx & (ED - 1);
      Wx[n][k] = Wih[((n >> 3) * HD + u0 + (n & 7)) * ED + k];
    }
    const float bi0 = bsum[0 * HD + u0 + j2], bi1 = bsum[0 * HD + u0 + j2 + 1];
    const float bf0 = bsum[1 * HD + u0 + j2], bf1 = bsum[1 * HD + u0 + j2 + 1];
    const float bg0 = bsum[2 * HD + u0 + j2], bg1 = bsum[2 * HD + u0 + j2 + 1];
    const float bo0 = bsum[3 * HD + u0 + j2], bo1 = bsum[3 * HD + u0 + j2 + 1];
    float c0 = 0.f, c1 = 0.f;
    __syncthreads();  // Wr/Wx + go_lds published

    for (int t = 0; t < ST; ++t) {
      const int step = phase * ST + t;
      u32* hxout = hx32 + (size_t)(step + 1) * SLOT32 + blk * 256;
      const bf16* xin = Xall + t * (NBAT * ED);

      // ---- x-part first: overlaps peers' fire propagation ----
      f32x4 acc1 = {0.f, 0.f, 0.f, 0.f};
      #pragma unroll
      for (int kk = 0; kk < ED / 32; ++kk) {
        bf16x8 av = *(const bf16x8*)(xin + arow * ED + kk * 32 + kc);
        bf16x8 bv = *(const bf16x8*)(&Wx[brow][kk * 32 + kc]);
        acc1 = __builtin_amdgcn_mfma_f32_16x16x32_bf16(av, bv, acc1, 0, 0, 0);
      }

      // ---- wait for h(step): wave0 fabric poll + LDS bounce ----
      if (step > 0) {
        if (wid == 0) {
          u32 f = __hip_atomic_load(&flags[lane], __ATOMIC_RELAXED,
                                    __HIP_MEMORY_SCOPE_AGENT);
          while (!__all((int)(f >= (u32)step))) {
            __builtin_amdgcn_s_sleep(1);
            f = __hip_atomic_load(&flags[lane], __ATOMIC_RELAXED,
                                  __HIP_MEMORY_SCOPE_AGENT);
          }
          if (lane == 0)
            __hip_atomic_store(&go_lds, (u32)step, __ATOMIC_RELAXED,
                               __HIP_MEMORY_SCOPE_WORKGROUP);
        } else {
          u32 g = __hip_atomic_load(&go_lds, __ATOMIC_RELAXED,
                                    __HIP_MEMORY_SCOPE_WORKGROUP);
          while (g < (u32)step) {
            __builtin_amdgcn_s_sleep(1);
            g = __hip_atomic_load(&go_lds, __ATOMIC_RELAXED,
                                  __HIP_MEMORY_SCOPE_WORKGROUP);
          }
        }
        __builtin_amdgcn_fence(__ATOMIC_ACQUIRE, "wavefront");
        __builtin_amdgcn_sched_barrier(0);
      }

      // ---- h-part: 16 chunks, plain cached cold-miss loads ----
      const bf16* hbase = (const bf16*)(hx32 + (size_t)step * SLOT32);
      const bf16* hptr  = hbase + (size_t)hi * 512 + arow * 8;
      f32x4 accA = {0.f, 0.f, 0.f, 0.f};
      f32x4 accB = {0.f, 0.f, 0.f, 0.f};
      #pragma unroll
      for (int kk = 0; kk < 16; kk += 2) {
        bf16x8 a0 = *(const bf16x8*)(hptr + (size_t)kk * 2048);
        bf16x8 a1 = *(const bf16x8*)(hptr + (size_t)(kk + 1) * 2048);
        bf16x8 b0 = *(const bf16x8*)(&Wr[brow][kk * 32 + kc]);
        bf16x8 b1 = *(const bf16x8*)(&Wr[brow][(kk + 1) * 32 + kc]);
        accA = __builtin_amdgcn_mfma_f32_16x16x32_bf16(a0, b0, accA, 0, 0, 0);
        accB = __builtin_amdgcn_mfma_f32_16x16x32_bf16(a1, b1, accB, 0, 0, 0);
      }
      #pragma unroll
      for (int r = 0; r < 4; ++r)
        gl[16 * wm + (lane >> 4) * 4 + r][16 * wn + r16] = accA[r] + accB[r] + acc1[r];
      __syncthreads();

      // elementwise LSTM cell: 256 threads, two adjacent units each
      if (tid < 256) {
        float gi0 = gl[eb][j2]      + bi0, gi1 = gl[eb][j2 + 1]  + bi1;
        float gf0 = gl[eb][8 + j2]  + bf0, gf1 = gl[eb][9 + j2]  + bf1;
        float gg0 = gl[eb][16 + j2] + bg0, gg1 = gl[eb][17 + j2] + bg1;
        float go0 = gl[eb][24 + j2] + bo0, go1 = gl[eb][25 + j2] + bo1;
        bool upd = (phase == 1) || (t < elen);
        float cn0 = sigm(gf0) * c0 + sigm(gi0) * tanhf(gg0);
        float cn1 = sigm(gf1) * c1 + sigm(gi1) * tanhf(gg1);
        float hn0 = sigm(go0) * tanhf(cn0);
        float hn1 = sigm(go1) * tanhf(cn1);
        if (upd) {
          c0 = cn0; c1 = cn1;
          union { u32 u; bf16 h[2]; } pk;
          pk.h[0] = (bf16)hn0; pk.h[1] = (bf16)hn1;
          hp = pk.u;
        }
        // full-line bypass store: contiguous 1 KB per block
        __hip_atomic_store(&hxout[tid], hp, __ATOMIC_RELAXED,
                           __HIP_MEMORY_SCOPE_AGENT);
        // decoder h also plain-stored to [t][b][h] for k_logits
        if (phase == 1)
          hs32[t * (NBAT * HD / 2) + eb * (HD / 2) + blk * 4 + (tid & 3)] = hp;
      }

      // drain bypass stores (vmcnt(0) per wave) + gl-reuse guard, then fire
      __syncthreads();
      if (step < 2 * ST - 1 && tid == 0)
        __hip_atomic_store(&flags[blk], (u32)(step + 1), __ATOMIC_RELAXED,
                           __HIP_MEMORY_SCOPE_AGENT);
    }
  }
}

// ---------------- output projection GEMM ----------------
// logits[b][t][v] = sum_h hs[t][b][h] * lin_W[v][h] + lin_b[v]
// M = ST*NBAT = 4096 (row m = t*64+b), N = VO = 32000, K = HD = 512.
// 128x128 tile, BK=64, 4 waves each owning a 64x64 quadrant (4x4 frags).
// XCD-aware bijective swizzle: 8000 blocks, 8000 % 8 == 0.
__global__ __launch_bounds__(256, 2) void k_logits(
    const bf16* __restrict__ hsb, const bf16* __restrict__ Wb,
    const float* __restrict__ linb, float* __restrict__ out)
{
  __shared__ __align__(16) bf16 As[128][72];  // +8 pad -> conflict-free frag reads
  __shared__ __align__(16) bf16 Bs[128][72];
  const int tid  = threadIdx.x;
  const int lane = tid & 63;
  const int wid  = tid >> 6;
  const int wm   = wid >> 1, wn = wid & 1;

  const int flat = blockIdx.y * gridDim.x + blockIdx.x;   // 0..7999
  const int swz  = (flat & 7) * 1000 + (flat >> 3);       // bijective (8000%8==0)
  const int bn   = (swz % (VO / 128)) * 128;
  const int bm   = (swz / (VO / 128)) * 128;

  const int r16  = lane & 15, kh = lane >> 4;

  f32x4 acc[4][4];
  #pragma unroll
  for (int i = 0; i < 4; ++i)
    #pragma unroll
    for (int j = 0; j < 4; ++j) acc[i][j] = (f32x4){0.f, 0.f, 0.f, 0.f};

  const int srow = tid >> 3;        // 0..31
  const int scol = (tid & 7) * 8;   // 0..56

  for (int kt = 0; kt < HD / 64; ++kt) {
    __syncthreads();
    #pragma unroll
    for (int p = 0; p < 4; ++p) {
      int row = p * 32 + srow;
      *(bf16x8*)(&As[row][scol]) =
          *(const bf16x8*)(hsb + (size_t)(bm + row) * HD + kt * 64 + scol);
      *(bf16x8*)(&Bs[row][scol]) =
          *(const bf16x8*)(Wb + (size_t)(bn + row) * HD + kt * 64 + scol);
    }
    __syncthreads();
    #pragma unroll
    for (int kk = 0; kk < 2; ++kk) {
      bf16x8 af[4], bfv[4];
      #pragma unroll
      for (int i = 0; i < 4; ++i)
        af[i] = *(const bf16x8*)(&As[64 * wm + 16 * i + r16][kk * 32 + kh * 8]);
      #pragma unroll
      for (int j = 0; j < 4; ++j)
        bfv[j] = *(const bf16x8*)(&Bs[64 * wn + 16 * j + r16][kk * 32 + kh * 8]);
      #pragma unroll
      for (int i = 0; i < 4; ++i)
        #pragma unroll
        for (int j = 0; j < 4; ++j)
          acc[i][j] = __builtin_amdgcn_mfma_f32_16x16x32_bf16(af[i], bfv[j], acc[i][j], 0, 0, 0);
    }
  }

  #pragma unroll
  for (int j = 0; j < 4; ++j) {
    int ncol = bn + 64 * wn + 16 * j + r16;
    float bias = linb[ncol];
    #pragma unroll
    for (int i = 0; i < 4; ++i) {
      int mbase = bm + 64 * wm + 16 * i + kh * 4;
      #pragma unroll
      for (int r = 0; r < 4; ++r) {
        int m = mbase + r;
        int b = m & 63, t = m >> 6;
        out[(size_t)(b * ST + t) * VO + ncol] = acc[i][j][r] + bias;
      }
    }
  }
}

// ---------------- host ----------------

extern "C" void kernel_launch(void* const* d_in, const int* in_sizes, int n_in,
                              void* d_out, int out_size, void* d_ws, size_t ws_size,
                              hipStream_t stream) {
  const int*   toks = (const int*)d_in[0];
  const float* emb  = (const float*)d_in[1];
  const float* eWih = (const float*)d_in[2];
  const float* eWhh = (const float*)d_in[3];
  const float* ebih = (const float*)d_in[4];
  const float* ebhh = (const float*)d_in[5];
  const float* dWih = (const float*)d_in[6];
  const float* dWhh = (const float*)d_in[7];
  const float* dbih = (const float*)d_in[8];
  const float* dbhh = (const float*)d_in[9];
  const float* linW = (const float*)d_in[10];
  const float* linb = (const float*)d_in[11];
  float* out = (float*)d_out;

  char* ws = (char*)d_ws;
  size_t off = 0;
  auto alloc = [&](size_t bytes) {
    void* p = ws + off;
    off = (off + bytes + 255) & ~(size_t)255;
    return p;
  };
  bf16* encX  = (bf16*)alloc((size_t)ST * NBAT * ED * 2);
  bf16* decX  = (bf16*)alloc((size_t)ST * NBAT * ED * 2);
  bf16* WihEb = (bf16*)alloc((size_t)G4 * ED * 2);
  bf16* WhhEb = (bf16*)alloc((size_t)G4 * HD * 2);
  bf16* WihDb = (bf16*)alloc((size_t)G4 * ED * 2);
  bf16* WhhDb = (bf16*)alloc((size_t)G4 * HD * 2);
  bf16* WbL   = (bf16*)alloc((size_t)VO * HD * 2);
  float* bsumE = (float*)alloc(G4 * 4);
  float* bsumD = (float*)alloc(G4 * 4);
  u32*  hx    = (u32*)alloc((size_t)(2 * ST + 1) * SLOT32 * 4);  // 129 x 64 KB
  u32*  hs    = (u32*)alloc((size_t)ST * NBAT * HD * 2);         // [t][b][h]
  int*  len   = (int*)alloc(NBAT * 4);
  u32*  flags = (u32*)alloc(4096);

  // slot 0 (h(0)=0) + flags must be clean every launch
  hipMemsetAsync(hx, 0, (size_t)SLOT32 * 4, stream);
  hipMemsetAsync(flags, 0, 4096, stream);

  k_lengths<<<1, 64, 0, stream>>>(toks, len);
  k_bias<<<(G4 + 255) / 256, 256, 0, stream>>>(ebih, ebhh, bsumE);
  k_bias<<<(G4 + 255) / 256, 256, 0, stream>>>(dbih, dbhh, bsumD);
  k_cast<<<(G4 * ED + 255) / 256, 256, 0, stream>>>(eWih, WihEb, G4 * ED);
  k_cast<<<(G4 * HD + 255) / 256, 256, 0, stream>>>(eWhh, WhhEb, G4 * HD);
  k_cast<<<(G4 * ED + 255) / 256, 256, 0, stream>>>(dWih, WihDb, G4 * ED);
  k_cast<<<(G4 * HD + 255) / 256, 256, 0, stream>>>(dWhh, WhhDb, G4 * HD);
  k_cast<<<(VO * HD + 255) / 256, 256, 0, stream>>>(linW, WbL, VO * HD);
  k_gather<<<(ST * NBAT * ED + 255) / 256, 256, 0, stream>>>(toks, emb, encX, decX);

  k_lstm<<<NWORK, 512, 0, stream>>>(encX, decX, WihEb, WhhEb, WihDb, WhhDb,
                                    bsumE, bsumD, len, hx, hs, flags);

  k_logits<<<dim3(VO / 128, (ST * NBAT) / 128), 256, 0, stream>>>(
      (const bf16*)hs, WbL, linb, out);
}

// Round 11
// 834.483 us; speedup vs baseline: 2.1024x; 1.1968x over previous
//
#include <hip/hip_runtime.h>
#include <math.h>

// Problem constants
#define ST 64      // sequence length T
#define NBAT 64    // batch B
#define ED 256     // embedding dim E
#define HD 512     // hidden dim H
#define G4 2048    // 4*H
#define VO 32000   // vocab
#define NWORK 64               // recurrence blocks
#define NLOG 192               // logits worker blocks
#define NTILES (VO / 128)      // 250 vocab n-tiles
#define SLOT32 (NBAT * HD / 2) // u32s per h slot (64 KB)

typedef unsigned int u32;
typedef __bf16 bf16;
typedef bf16 bf16x8 __attribute__((ext_vector_type(8)));
typedef float f32x4 __attribute__((ext_vector_type(4)));

__device__ __forceinline__ float sigm(float x) { return 1.f / (1.f + expf(-x)); }

// ---------------- prep kernels ----------------

__global__ void k_lengths(const int* __restrict__ toks, int* __restrict__ len) {
  int b = threadIdx.x;
  if (b < NBAT) {
    int n = 0;
    for (int t = 0; t < ST; ++t) n += (toks[b * ST + t] != 0) ? 1 : 0;
    len[b] = n;
  }
}

__global__ void k_cast(const float* __restrict__ src, bf16* __restrict__ dst, int n) {
  int i = blockIdx.x * blockDim.x + threadIdx.x;
  if (i < n) dst[i] = (bf16)src[i];
}

__global__ void k_bias(const float* __restrict__ a, const float* __restrict__ b,
                       float* __restrict__ o) {
  int i = blockIdx.x * blockDim.x + threadIdx.x;
  if (i < G4) o[i] = a[i] + b[i];
}

// encX[t][b][e] = emb[toks[b][t]][e]; decX[t][b][e] = emb[t==0 ? 1 : toks[b][t-1]][e]
__global__ void k_gather(const int* __restrict__ toks, const float* __restrict__ emb,
                         bf16* __restrict__ encX, bf16* __restrict__ decX) {
  int i = blockIdx.x * blockDim.x + threadIdx.x;
  if (i >= ST * NBAT * ED) return;
  int e = i % ED;
  int tb = i / ED;
  int b = tb % NBAT;
  int t = tb / NBAT;
  int te = toks[b * ST + t];
  encX[i] = (bf16)emb[te * ED + e];
  int td = (t == 0) ? 1 : toks[b * ST + t - 1];
  decX[i] = (bf16)emb[td * ED + e];
}

// ---------------- fused persistent kernel ----------------
//
// 256 blocks, exactly 1 per CU (LDS 133 KB forces it; r9 proved >128 KB
// static LDS works). Blocks 0..63: round-10 recurrence (5.2 us/step floor).
// Blocks 64..255: logits workers using the otherwise-idle 192 CUs.
//
// Recurrence sync (unchanged from r10): full-line bypass h-stores to
// per-step slots; __syncthreads drains acks; tid0 fires flags[blk]=step+1
// (now for ALL steps incl. 127 -> flags=128). Wave0 polls the 64 dense
// flags, LDS-bounces go to waves 1-7. Block 0's wave0 additionally
// publishes decgo=step (single broadcast line) -- it already computes the
// all-fired condition, so logits workers never touch the flag lines
// (r8's congestion lesson).
//
// Logits worker lid: owns n-tiles {lid, lid+192} of 250. Stages its B-tile
// (128 cols x 512 K bf16) into LDS ONCE per tile, then for t=0..63:
// lazy-poll decgo >= 65+t (sleep between polls; latency slack is huge),
// read A = h(65+t) straight from the hx slot (same chunk addressing as the
// recurrence h-load; bypass-written, cold-by-construction, flag-gated ->
// fresh), 512 MFMAs, write out rows b*ST+t. Work arrives at ~2 tiles/block
// per step vs ~2-3 us compute -> workers keep pace; tail ~ tens of us.
__global__ __launch_bounds__(512, 2) void k_fused(
    const bf16* __restrict__ encX, const bf16* __restrict__ decX,
    const bf16* __restrict__ WihE, const bf16* __restrict__ WhhE,
    const bf16* __restrict__ WihD, const bf16* __restrict__ WhhD,
    const float* __restrict__ bsumE, const float* __restrict__ bsumD,
    const int* __restrict__ len,
    const bf16* __restrict__ WbL, const float* __restrict__ linb,
    float* __restrict__ out,
    u32* __restrict__ hx32,    // [2*ST+1][NWORK][NBAT][8/2] per-step h slots
    u32* flags,                // [64] dense worker progress
    u32* decgo)                // [1] block0 broadcast of confirmed step
{
  __shared__ __align__(16) char smem[133632];

  const int tid  = threadIdx.x;
  const int lane = tid & 63;
  const int wid  = tid >> 6;
  const int blk  = blockIdx.x;
  const int r16  = lane & 15;
  const int kh   = lane >> 4;
  const int kc   = kh * 8;

  if (blk < NWORK) {
    // ================= recurrence block =================
    auto Wr = (bf16(*)[HD + 8])smem;                 // 32 x 520 bf16
    auto Wx = (bf16(*)[ED + 8])(smem + 33280);       // 32 x 264 bf16
    auto gl = (float(*)[33])(smem + 50176);          // 64 x 33 f32
    u32* go_lds = (u32*)(smem + 58624);

    const int wm   = wid & 3;        // m-fragment (batch rows 16*wm..)
    const int wn   = wid >> 2;       // n-fragment (cols 16*wn..), 0..1
    const int u0   = blk * 8;
    const int hi   = kh;             // which 8-chunk of the 32-K slice
    const int arow = 16 * wm + r16;  // batch row for A-frags
    const int brow = 16 * wn + r16;  // LDS row for B-frags

    const int eb   = (tid & 255) >> 2;   // 0..63
    const int j2   = (tid & 3) * 2;
    const int elen = len[eb];

    if (tid == 0) *go_lds = 0;
    u32 hp = 0;

    for (int phase = 0; phase < 2; ++phase) {
      const bf16* Wih  = phase ? WihD : WihE;
      const bf16* Whh  = phase ? WhhD : WhhE;
      const float* bsum = phase ? bsumD : bsumE;
      const bf16* Xall = phase ? decX : encX;

      for (int idx = tid; idx < 32 * HD; idx += 512) {
        int n = idx >> 9, k = idx & (HD - 1);
        Wr[n][k] = Whh[((n >> 3) * HD + u0 + (n & 7)) * HD + k];
      }
      for (int idx = tid; idx < 32 * ED; idx += 512) {
        int n = idx >> 8, k = idx & (ED - 1);
        Wx[n][k] = Wih[((n >> 3) * HD + u0 + (n & 7)) * ED + k];
      }
      const float bi0 = bsum[0 * HD + u0 + j2], bi1 = bsum[0 * HD + u0 + j2 + 1];
      const float bf0 = bsum[1 * HD + u0 + j2], bf1 = bsum[1 * HD + u0 + j2 + 1];
      const float bg0 = bsum[2 * HD + u0 + j2], bg1 = bsum[2 * HD + u0 + j2 + 1];
      const float bo0 = bsum[3 * HD + u0 + j2], bo1 = bsum[3 * HD + u0 + j2 + 1];
      float c0 = 0.f, c1 = 0.f;
      __syncthreads();

      for (int t = 0; t < ST; ++t) {
        const int step = phase * ST + t;
        u32* hxout = hx32 + (size_t)(step + 1) * SLOT32 + blk * 256;
        const bf16* xin = Xall + t * (NBAT * ED);

        // x-part first: overlaps peers' fire propagation
        f32x4 acc1 = {0.f, 0.f, 0.f, 0.f};
        #pragma unroll
        for (int kk = 0; kk < ED / 32; ++kk) {
          bf16x8 av = *(const bf16x8*)(xin + arow * ED + kk * 32 + kc);
          bf16x8 bv = *(const bf16x8*)(&Wx[brow][kk * 32 + kc]);
          acc1 = __builtin_amdgcn_mfma_f32_16x16x32_bf16(av, bv, acc1, 0, 0, 0);
        }

        // wait for h(step): wave0 fabric poll + LDS bounce
        if (step > 0) {
          if (wid == 0) {
            u32 f = __hip_atomic_load(&flags[lane], __ATOMIC_RELAXED,
                                      __HIP_MEMORY_SCOPE_AGENT);
            while (!__all((int)(f >= (u32)step))) {
              __builtin_amdgcn_s_sleep(1);
              f = __hip_atomic_load(&flags[lane], __ATOMIC_RELAXED,
                                    __HIP_MEMORY_SCOPE_AGENT);
            }
            if (lane == 0) {
              __hip_atomic_store(go_lds, (u32)step, __ATOMIC_RELAXED,
                                 __HIP_MEMORY_SCOPE_WORKGROUP);
              if (blk == 0)
                __hip_atomic_store(decgo, (u32)step, __ATOMIC_RELAXED,
                                   __HIP_MEMORY_SCOPE_AGENT);
            }
          } else {
            u32 g = __hip_atomic_load(go_lds, __ATOMIC_RELAXED,
                                      __HIP_MEMORY_SCOPE_WORKGROUP);
            while (g < (u32)step) {
              __builtin_amdgcn_s_sleep(1);
              g = __hip_atomic_load(go_lds, __ATOMIC_RELAXED,
                                    __HIP_MEMORY_SCOPE_WORKGROUP);
            }
          }
          __builtin_amdgcn_fence(__ATOMIC_ACQUIRE, "wavefront");
          __builtin_amdgcn_sched_barrier(0);
        }

        // h-part: 16 chunks, plain cached cold-miss loads
        const bf16* hbase = (const bf16*)(hx32 + (size_t)step * SLOT32);
        const bf16* hptr  = hbase + (size_t)hi * 512 + arow * 8;
        f32x4 accA = {0.f, 0.f, 0.f, 0.f};
        f32x4 accB = {0.f, 0.f, 0.f, 0.f};
        #pragma unroll
        for (int kk = 0; kk < 16; kk += 2) {
          bf16x8 a0 = *(const bf16x8*)(hptr + (size_t)kk * 2048);
          bf16x8 a1 = *(const bf16x8*)(hptr + (size_t)(kk + 1) * 2048);
          bf16x8 b0 = *(const bf16x8*)(&Wr[brow][kk * 32 + kc]);
          bf16x8 b1 = *(const bf16x8*)(&Wr[brow][(kk + 1) * 32 + kc]);
          accA = __builtin_amdgcn_mfma_f32_16x16x32_bf16(a0, b0, accA, 0, 0, 0);
          accB = __builtin_amdgcn_mfma_f32_16x16x32_bf16(a1, b1, accB, 0, 0, 0);
        }
        #pragma unroll
        for (int r = 0; r < 4; ++r)
          gl[16 * wm + kh * 4 + r][16 * wn + r16] = accA[r] + accB[r] + acc1[r];
        __syncthreads();

        // elementwise cell: 256 threads, two adjacent units each
        if (tid < 256) {
          float gi0 = gl[eb][j2]      + bi0, gi1 = gl[eb][j2 + 1]  + bi1;
          float gf0 = gl[eb][8 + j2]  + bf0, gf1 = gl[eb][9 + j2]  + bf1;
          float gg0 = gl[eb][16 + j2] + bg0, gg1 = gl[eb][17 + j2] + bg1;
          float go0 = gl[eb][24 + j2] + bo0, go1 = gl[eb][25 + j2] + bo1;
          bool upd = (phase == 1) || (t < elen);
          float cn0 = sigm(gf0) * c0 + sigm(gi0) * tanhf(gg0);
          float cn1 = sigm(gf1) * c1 + sigm(gi1) * tanhf(gg1);
          float hn0 = sigm(go0) * tanhf(cn0);
          float hn1 = sigm(go1) * tanhf(cn1);
          if (upd) {
            c0 = cn0; c1 = cn1;
            union { u32 u; bf16 h[2]; } pk;
            pk.h[0] = (bf16)hn0; pk.h[1] = (bf16)hn1;
            hp = pk.u;
          }
          __hip_atomic_store(&hxout[tid], hp, __ATOMIC_RELAXED,
                             __HIP_MEMORY_SCOPE_AGENT);
        }

        // drain bypass stores + gl-reuse guard, then fire (ALL steps)
        __syncthreads();
        if (tid == 0)
          __hip_atomic_store(&flags[blk], (u32)(step + 1), __ATOMIC_RELAXED,
                             __HIP_MEMORY_SCOPE_AGENT);
      }
    }

    // block0: confirm the final fire (flags=128) for the logits workers
    if (blk == 0 && wid == 0) {
      u32 f = __hip_atomic_load(&flags[lane], __ATOMIC_RELAXED,
                                __HIP_MEMORY_SCOPE_AGENT);
      while (!__all((int)(f >= (u32)(2 * ST)))) {
        __builtin_amdgcn_s_sleep(1);
        f = __hip_atomic_load(&flags[lane], __ATOMIC_RELAXED,
                              __HIP_MEMORY_SCOPE_AGENT);
      }
      if (lane == 0)
        __hip_atomic_store(decgo, (u32)(2 * ST), __ATOMIC_RELAXED,
                           __HIP_MEMORY_SCOPE_AGENT);
    }
  } else {
    // ================= logits worker =================
    auto Bs = (bf16(*)[HD + 8])smem;           // 128 x 520 bf16 (133120 B)
    u32* bgo = (u32*)(smem + 133120);
    const int lid = blk - NWORK;               // 0..191
    const int wm = wid & 3, wn = wid >> 2;
    const int arow = 16 * wm + r16;

    if (tid == 0) *bgo = 0;

    for (int nt = lid; nt < NTILES; nt += NLOG) {
      __syncthreads();  // previous tile fully consumed before restage
      for (int idx = tid; idx < 128 * (HD / 8); idx += 512) {
        int n = idx >> 6, k8 = (idx & 63) * 8;
        *(bf16x8*)&Bs[n][k8] =
            *(const bf16x8*)(WbL + (size_t)(nt * 128 + n) * HD + k8);
      }
      __syncthreads();

      for (int t = 0; t < ST; ++t) {
        const u32 target = (u32)(ST + 1 + t);
        if (wid == 0) {
          u32 v = __hip_atomic_load(decgo, __ATOMIC_RELAXED,
                                    __HIP_MEMORY_SCOPE_AGENT);
          while (v < target) {
            __builtin_amdgcn_s_sleep(8);
            v = __hip_atomic_load(decgo, __ATOMIC_RELAXED,
                                  __HIP_MEMORY_SCOPE_AGENT);
          }
          if (lane == 0)
            __hip_atomic_store(bgo, v, __ATOMIC_RELAXED,
                               __HIP_MEMORY_SCOPE_WORKGROUP);
        } else {
          u32 g = __hip_atomic_load(bgo, __ATOMIC_RELAXED,
                                    __HIP_MEMORY_SCOPE_WORKGROUP);
          while (g < target) {
            __builtin_amdgcn_s_sleep(4);
            g = __hip_atomic_load(bgo, __ATOMIC_RELAXED,
                                  __HIP_MEMORY_SCOPE_WORKGROUP);
          }
        }
        __builtin_amdgcn_fence(__ATOMIC_ACQUIRE, "wavefront");
        __builtin_amdgcn_sched_barrier(0);

        // A = h(65+t) from the coherent slot (flag-gated -> fresh)
        const bf16* slotA = (const bf16*)(hx32 + (size_t)target * SLOT32);
        const bf16* aptr  = slotA + (size_t)kh * 512 + arow * 8;
        f32x4 acc[4];
        #pragma unroll
        for (int jj = 0; jj < 4; ++jj) acc[jj] = (f32x4){0.f, 0.f, 0.f, 0.f};
        #pragma unroll
        for (int kk = 0; kk < 16; ++kk) {
          bf16x8 av = *(const bf16x8*)(aptr + (size_t)kk * 2048);
          #pragma unroll
          for (int jj = 0; jj < 4; ++jj) {
            bf16x8 bv = *(const bf16x8*)(&Bs[64 * wn + 16 * jj + r16][kk * 32 + kc]);
            acc[jj] = __builtin_amdgcn_mfma_f32_16x16x32_bf16(av, bv, acc[jj], 0, 0, 0);
          }
        }
        #pragma unroll
        for (int jj = 0; jj < 4; ++jj) {
          int col = nt * 128 + 64 * wn + 16 * jj + r16;
          float bias = linb[col];
          #pragma unroll
          for (int r = 0; r < 4; ++r) {
            int b = 16 * wm + kh * 4 + r;
            out[((size_t)b * ST + t) * VO + col] = acc[jj][r] + bias;
          }
        }
      }
    }
  }
}

// ---------------- host ----------------

extern "C" void kernel_launch(void* const* d_in, const int* in_sizes, int n_in,
                              void* d_out, int out_size, void* d_ws, size_t ws_size,
                              hipStream_t stream) {
  const int*   toks = (const int*)d_in[0];
  const float* emb  = (const float*)d_in[1];
  const float* eWih = (const float*)d_in[2];
  const float* eWhh = (const float*)d_in[3];
  const float* ebih = (const float*)d_in[4];
  const float* ebhh = (const float*)d_in[5];
  const float* dWih = (const float*)d_in[6];
  const float* dWhh = (const float*)d_in[7];
  const float* dbih = (const float*)d_in[8];
  const float* dbhh = (const float*)d_in[9];
  const float* linW = (const float*)d_in[10];
  const float* linb = (const float*)d_in[11];
  float* out = (float*)d_out;

  char* ws = (char*)d_ws;
  size_t off = 0;
  auto alloc = [&](size_t bytes) {
    void* p = ws + off;
    off = (off + bytes + 255) & ~(size_t)255;
    return p;
  };
  bf16* encX  = (bf16*)alloc((size_t)ST * NBAT * ED * 2);
  bf16* decX  = (bf16*)alloc((size_t)ST * NBAT * ED * 2);
  bf16* WihEb = (bf16*)alloc((size_t)G4 * ED * 2);
  bf16* WhhEb = (bf16*)alloc((size_t)G4 * HD * 2);
  bf16* WihDb = (bf16*)alloc((size_t)G4 * ED * 2);
  bf16* WhhDb = (bf16*)alloc((size_t)G4 * HD * 2);
  bf16* WbL   = (bf16*)alloc((size_t)VO * HD * 2);
  float* bsumE = (float*)alloc(G4 * 4);
  float* bsumD = (float*)alloc(G4 * 4);
  u32*  hx    = (u32*)alloc((size_t)(2 * ST + 1) * SLOT32 * 4);  // 129 x 64 KB
  int*  len   = (int*)alloc(NBAT * 4);
  u32*  flags = (u32*)alloc(4096);
  u32*  decgo = flags + 64;   // own line (byte 256), inside memset region

  // slot 0 (h(0)=0) + flags/decgo must be clean every launch
  hipMemsetAsync(hx, 0, (size_t)SLOT32 * 4, stream);
  hipMemsetAsync(flags, 0, 4096, stream);

  k_lengths<<<1, 64, 0, stream>>>(toks, len);
  k_bias<<<(G4 + 255) / 256, 256, 0, stream>>>(ebih, ebhh, bsumE);
  k_bias<<<(G4 + 255) / 256, 256, 0, stream>>>(dbih, dbhh, bsumD);
  k_cast<<<(G4 * ED + 255) / 256, 256, 0, stream>>>(eWih, WihEb, G4 * ED);
  k_cast<<<(G4 * HD + 255) / 256, 256, 0, stream>>>(eWhh, WhhEb, G4 * HD);
  k_cast<<<(G4 * ED + 255) / 256, 256, 0, stream>>>(dWih, WihDb, G4 * ED);
  k_cast<<<(G4 * HD + 255) / 256, 256, 0, stream>>>(dWhh, WhhDb, G4 * HD);
  k_cast<<<(VO * HD + 255) / 256, 256, 0, stream>>>(linW, WbL, VO * HD);
  k_gather<<<(ST * NBAT * ED + 255) / 256, 256, 0, stream>>>(toks, emb, encX, decX);

  k_fused<<<NWORK + NLOG, 512, 0, stream>>>(
      encX, decX, WihEb, WhhEb, WihDb, WhhDb, bsumE, bsumD, len,
      WbL, linb, out, hx, flags, decgo);
}